// Round 11
// baseline (289.674 us; speedup 1.0000x reference)
//
#include <hip/hip_runtime.h>
#include <hip/hip_bf16.h>

#define NN 10000
#define NE 160000
#define NH 8
#define NC 64
#define NF 512   // NH*NC
#define NEG_SLOPE 0.2f
#define SEPS 1e-16f
#define L2E 1.44269504f

typedef __attribute__((ext_vector_type(8))) short s8v;   // 8 bf16 (4 VGPRs)
typedef __attribute__((ext_vector_type(4))) float f4v;   // MFMA accumulator

__device__ __forceinline__ float lrelu(float x) { return x > 0.f ? x : NEG_SLOPE * x; }

__device__ __forceinline__ unsigned short bf16_rn(float f) {
  unsigned int u = __float_as_uint(f);
  return (unsigned short)((u + 0x7FFFu + ((u >> 16) & 1u)) >> 16);
}
__device__ __forceinline__ float bf16_to_f32(unsigned short h) {
  return __uint_as_float(((unsigned int)h) << 16);
}

// ------------------------- CSR build -------------------------
__global__ void hist_kernel(const int* __restrict__ dst, int* __restrict__ counts) {
  int e = blockIdx.x * blockDim.x + threadIdx.x;
  if (e < NE) atomicAdd(&counts[dst[e]], 1);
}

__global__ __launch_bounds__(1024) void scan_fast(const int* __restrict__ counts,
                                                  int* __restrict__ row_ptr) {
  __shared__ int part[1024];
  const int tid = threadIdx.x;
  const int base = tid * 16;
  int loc[16];
  int s = 0;
#pragma unroll
  for (int i = 0; i < 16; ++i) {
    int idx = base + i;
    int v = (idx < NN) ? counts[idx] : 0;
    loc[i] = s;
    s += v;
  }
  part[tid] = s;
  __syncthreads();
  for (int off = 1; off < 1024; off <<= 1) {
    int t = (tid >= off) ? part[tid - off] : 0;
    __syncthreads();
    part[tid] += t;
    __syncthreads();
  }
  int pre = (tid > 0) ? part[tid - 1] : 0;
#pragma unroll
  for (int i = 0; i < 16; ++i) {
    int idx = base + i;
    if (idx < NN) row_ptr[idx] = pre + loc[i];
  }
  if (tid == 1023) row_ptr[NN] = part[1023];
}

// store src VALUES sorted by dst (removes a gather level in agg)
__global__ void scatter_src(const int* __restrict__ src, const int* __restrict__ dst,
                            const int* __restrict__ row_ptr, int* __restrict__ cursor,
                            int* __restrict__ csr_src) {
  int e = blockIdx.x * blockDim.x + threadIdx.x;
  if (e < NE) {
    int d = dst[e];
    int r = atomicAdd(&cursor[d], 1);
    csr_src[row_ptr[d] + r] = src[e];
  }
}

// ---------------- f32 -> bf16 hi/lo split (elementwise) ----------------------
__global__ void split_kernel(const float* __restrict__ in, unsigned short* __restrict__ hi,
                             unsigned short* __restrict__ lo, int n4) {
  int i = blockIdx.x * blockDim.x + threadIdx.x;
  if (i < n4) {
    float4 v = ((const float4*)in)[i];
    float a[4] = {v.x, v.y, v.z, v.w};
    ushort4 h, l;
    unsigned short* hp = (unsigned short*)&h;
    unsigned short* lp = (unsigned short*)&l;
#pragma unroll
    for (int q = 0; q < 4; ++q) {
      unsigned short hb = bf16_rn(a[q]);
      hp[q] = hb;
      lp[q] = bf16_rn(a[q] - bf16_to_f32(hb));
    }
    ((ushort4*)hi)[i] = h;
    ((ushort4*)lo)[i] = l;
  }
}

// ------------- W[K][N] -> WT_hi/lo[N][K] transpose + split -------------------
__global__ __launch_bounds__(256) void tsplit_kernel(const float* __restrict__ W,
                                                     unsigned short* __restrict__ th,
                                                     unsigned short* __restrict__ tl,
                                                     int K, int N) {
  __shared__ float t[32][33];
  const int bx = blockIdx.x * 32;  // N base
  const int by = blockIdx.y * 32;  // K base
  const int lx = threadIdx.x & 31, ly = threadIdx.x >> 5;
#pragma unroll
  for (int r = 0; r < 32; r += 8)
    t[ly + r][lx] = W[(size_t)(by + ly + r) * N + bx + lx];
  __syncthreads();
#pragma unroll
  for (int r = 0; r < 32; r += 8) {
    float v = t[lx][ly + r];
    unsigned short hb = bf16_rn(v);
    size_t o = (size_t)(bx + ly + r) * K + by + lx;
    th[o] = hb;
    tl[o] = bf16_rn(v - bf16_to_f32(hb));
  }
}

// ---------------- MFMA GEMM with pre-split bf16 inputs (LDS-staged) ----------
// C[M][N] = A[M][K] @ B[K][N], B given transposed+split: BT[N][K].
// Tile 128x64, BK=32, 4 waves (2M x 2N). hi/lo 3-product MFMA.
// LDS fragment-major, slot unit 16B. [round-4 verified: absmax 3.05e-5]
#define GBM 128
#define GBN 64
#define GBK 32

__global__ __launch_bounds__(256) void gemm_bf16(const unsigned short* __restrict__ Ahi,
                                                 const unsigned short* __restrict__ Alo,
                                                 const unsigned short* __restrict__ BThi,
                                                 const unsigned short* __restrict__ BTlo,
                                                 float* __restrict__ C,
                                                 int M, int K, int N) {
  __shared__ s8v smem[1536];  // AH[512] AL[512] BH[256] BL[256]
  const int tid = threadIdx.x;
  const int m0 = blockIdx.y * GBM, n0 = blockIdx.x * GBN;
  const int wid = tid >> 6, lane = tid & 63;
  const int wm = wid >> 1, wn = wid & 1;
  const int lr = lane & 15, lb = lane >> 4;

  f4v acc[4][2];
  const f4v fzero = {0.f, 0.f, 0.f, 0.f};
#pragma unroll
  for (int m = 0; m < 4; ++m)
#pragma unroll
    for (int n = 0; n < 2; ++n) acc[m][n] = fzero;

  const int arow = tid >> 1, akh = tid & 1;
  const bool avalid = (m0 + arow) < M;
  const int aslot = ((arow >> 4) * 4 + akh * 2) * 16 + (arow & 15);
  const int bcol = tid >> 2, bkq = tid & 3;
  const int bslot = ((bcol >> 4) * 4 + bkq) * 16 + (bcol & 15);
  const s8v zv = {0, 0, 0, 0, 0, 0, 0, 0};

  for (int k0 = 0; k0 < K; k0 += GBK) {
    s8v a_h0 = zv, a_h1 = zv, a_l0 = zv, a_l1 = zv, b_h, b_l;
    if (avalid) {
      const unsigned short* ap = &Ahi[(size_t)(m0 + arow) * K + k0 + akh * 16];
      const unsigned short* alp = &Alo[(size_t)(m0 + arow) * K + k0 + akh * 16];
      a_h0 = *(const s8v*)ap;
      a_h1 = *(const s8v*)(ap + 8);
      a_l0 = *(const s8v*)alp;
      a_l1 = *(const s8v*)(alp + 8);
    }
    {
      const unsigned short* bp = &BThi[(size_t)(n0 + bcol) * K + k0 + bkq * 8];
      const unsigned short* blp = &BTlo[(size_t)(n0 + bcol) * K + k0 + bkq * 8];
      b_h = *(const s8v*)bp;
      b_l = *(const s8v*)blp;
    }
    __syncthreads();
    smem[aslot] = a_h0;
    smem[aslot + 16] = a_h1;
    smem[512 + aslot] = a_l0;
    smem[512 + aslot + 16] = a_l1;
    smem[1024 + bslot] = b_h;
    smem[1280 + bslot] = b_l;
    __syncthreads();
    s8v ah[4], al[4], bh[2], bl[2];
#pragma unroll
    for (int m = 0; m < 4; ++m) {
      int slot = ((wm * 4 + m) * 4 + lb) * 16 + lr;
      ah[m] = smem[slot];
      al[m] = smem[512 + slot];
    }
#pragma unroll
    for (int n = 0; n < 2; ++n) {
      int slot = ((wn * 2 + n) * 4 + lb) * 16 + lr;
      bh[n] = smem[1024 + slot];
      bl[n] = smem[1280 + slot];
    }
#pragma unroll
    for (int m = 0; m < 4; ++m)
#pragma unroll
      for (int n = 0; n < 2; ++n) {
        acc[m][n] = __builtin_amdgcn_mfma_f32_16x16x32_bf16(ah[m], bh[n], acc[m][n], 0, 0, 0);
        acc[m][n] = __builtin_amdgcn_mfma_f32_16x16x32_bf16(ah[m], bl[n], acc[m][n], 0, 0, 0);
        acc[m][n] = __builtin_amdgcn_mfma_f32_16x16x32_bf16(al[m], bh[n], acc[m][n], 0, 0, 0);
      }
  }
#pragma unroll
  for (int m = 0; m < 4; ++m) {
    int row = m0 + wm * 64 + m * 16 + lb * 4;
#pragma unroll
    for (int n = 0; n < 2; ++n) {
      int col = n0 + wn * 32 + n * 16 + lr;
#pragma unroll
      for (int j = 0; j < 4; ++j) {
        if (row + j < M) C[(size_t)(row + j) * N + col] = acc[m][n][j];
      }
    }
  }
}

// ------------------- per-node attention logits (4 nodes/block) ---------------
__global__ __launch_bounds__(256) void att_logits_v(const float* __restrict__ h,
                                                    const float* __restrict__ att_src,
                                                    const float* __restrict__ att_dst,
                                                    float* __restrict__ as_,
                                                    float* __restrict__ ad_) {
  const int n = blockIdx.x * 4 + (threadIdx.x >> 6);
  const int lane = threadIdx.x & 63;
  const float4* hp = (const float4*)&h[(size_t)n * NF];
  float4 v0 = hp[lane * 2], v1 = hp[lane * 2 + 1];
  const int base = lane * 8;
  const float4* sp = (const float4*)&att_src[base];
  const float4* dp = (const float4*)&att_dst[base];
  float4 s0 = sp[0], s1 = sp[1], d0 = dp[0], d1 = dp[1];
  float s = v0.x * s0.x + v0.y * s0.y + v0.z * s0.z + v0.w * s0.w +
            v1.x * s1.x + v1.y * s1.y + v1.z * s1.z + v1.w * s1.w;
  float d = v0.x * d0.x + v0.y * d0.y + v0.z * d0.z + v0.w * d0.w +
            v1.x * d1.x + v1.y * d1.y + v1.z * d1.z + v1.w * d1.w;
#pragma unroll
  for (int off = 1; off <= 4; off <<= 1) {
    s += __shfl_xor(s, off);
    d += __shfl_xor(d, off);
  }
  if ((lane & 7) == 0) {
    int hd = lane >> 3;
    as_[n * NH + hd] = s;
    ad_[n * NH + hd] = d;
  }
}

// ---------------- fused edge-softmax + softmax-aggregation -------------------
// 4 dst nodes per 256-thread block, one 64-lane wave per node (no cross-wave
// interaction, no barriers). 1-wave/block capped occupancy at ~43% (round 10:
// max-workgroups-per-CU limit); 4 waves/block lifts the ceiling to 32/CU.
// Edge src values shfl-broadcast from registers; 8 channels/lane (32B loads).
// Plain (non-shifted) softmax: logits O(1-10), f32 exp cannot overflow.
// NOTE: every __shfl must execute with a wave-uniform trip count (round-5 bug).
template <int SPLITOUT>
__global__ __launch_bounds__(256) void agg64(const float* __restrict__ h,
                                             const float* __restrict__ tptr,
                                             const int* __restrict__ csr_src,
                                             const int* __restrict__ row_ptr,
                                             const float* __restrict__ as_,
                                             const float* __restrict__ ad_,
                                             const float* __restrict__ bias,
                                             float* __restrict__ outf,
                                             unsigned short* __restrict__ outh,
                                             unsigned short* __restrict__ outl) {
  const int n = blockIdx.x * 4 + (threadIdx.x >> 6);
  const int lane = threadIdx.x & 63;
  const int start = row_ptr[n];
  const int deg = row_ptr[n + 1] - start;
  const int hd1 = lane & 7;   // pass-1 head
  const int jof = lane >> 3;  // pass-1 edge offset
  const int hd2 = lane >> 3;  // pass-2 head (channels c..c+7 all in this head)
  const int c = lane * 8;
  const float tl2 = tptr[0] * L2E;
  const float adv = ad_[n * NH + hd1];

  // ---- pass 1: per-head attention-softmax denominator ----
  // uniform trip count; shfl source clamped to an active lane; masked add
  float den = 0.f;
  for (int base = 0; base < deg; base += 64) {
    int cnt = min(deg - base, 64);
    int mysrc = csr_src[start + base + min(lane, cnt - 1)];
    int trips = (cnt + 7) >> 3;
    for (int i = 0; i < trips; ++i) {
      int j = jof + (i << 3);
      int sn = __shfl(mysrc, min(j, cnt - 1));
      float v = __builtin_exp2f(L2E * lrelu(as_[sn * NH + hd1] + adv));
      den += (j < cnt) ? v : 0.f;
    }
  }
  den += __shfl_xor(den, 8);
  den += __shfl_xor(den, 16);
  den += __shfl_xor(den, 32);
  float invd = 1.f / (den + SEPS);
  // lanes 0..7 hold heads 0..7; redistribute for pass-2 mapping
  float inv2 = __shfl(invd, hd2);
  float adv2 = __shfl(adv, hd2);

  // ---- pass 2: per-channel softmax-weighted aggregation ----
  float S[8], O[8];
#pragma unroll
  for (int q = 0; q < 8; ++q) { S[q] = 0.f; O[q] = 0.f; }
  for (int base = 0; base < deg; base += 64) {
    int cnt = min(deg - base, 64);
    int mysrc = csr_src[start + base + min(lane, cnt - 1)];
    for (int k = 0; k < cnt; ++k) {  // cnt is wave-uniform: all lanes active
      int sn = __shfl(mysrc, k);
      float av = as_[sn * NH + hd2];
      float alpha = __builtin_exp2f(L2E * lrelu(av + adv2)) * inv2;
      const float* hp = &h[(size_t)sn * NF + c];
      float4 h0 = *(const float4*)hp;
      float4 h1 = *(const float4*)(hp + 4);
      float hv[8] = {h0.x, h0.y, h0.z, h0.w, h1.x, h1.y, h1.z, h1.w};
#pragma unroll
      for (int q = 0; q < 8; ++q) {
        float m = hv[q] * alpha;
        float e = __builtin_exp2f(tl2 * m);
        S[q] += e;
        O[q] = fmaf(e, m, O[q]);
      }
    }
  }
  float r[8];
#pragma unroll
  for (int q = 0; q < 8; ++q)
    r[q] = fmaxf(O[q] / (S[q] + SEPS) + bias[c + q], 0.f);

  if (SPLITOUT) {
    short hh[8], ll[8];
#pragma unroll
    for (int q = 0; q < 8; ++q) {
      unsigned short hb = bf16_rn(r[q]);
      hh[q] = (short)hb;
      ll[q] = (short)bf16_rn(r[q] - bf16_to_f32(hb));
    }
    *(s8v*)(outh + (size_t)n * NF + c) = s8v{hh[0], hh[1], hh[2], hh[3], hh[4], hh[5], hh[6], hh[7]};
    *(s8v*)(outl + (size_t)n * NF + c) = s8v{ll[0], ll[1], ll[2], ll[3], ll[4], ll[5], ll[6], ll[7]};
  } else {
    float* op = &outf[(size_t)n * NF + c];
    *(float4*)op = make_float4(r[0], r[1], r[2], r[3]);
    *(float4*)(op + 4) = make_float4(r[4], r[5], r[6], r[7]);
  }
}

// ------------------------- launch -------------------------
extern "C" void kernel_launch(void* const* d_in, const int* in_sizes, int n_in,
                              void* d_out, int out_size, void* d_ws, size_t ws_size,
                              hipStream_t stream) {
  const float* x     = (const float*)d_in[0];
  const int*   ei    = (const int*)d_in[1];
  const float* W1    = (const float*)d_in[2];
  const float* at_s1 = (const float*)d_in[3];
  const float* at_d1 = (const float*)d_in[4];
  const float* b1    = (const float*)d_in[5];
  const float* t1    = (const float*)d_in[6];
  const float* W2    = (const float*)d_in[7];
  const float* at_s2 = (const float*)d_in[8];
  const float* at_d2 = (const float*)d_in[9];
  const float* b2    = (const float*)d_in[10];
  const float* t2    = (const float*)d_in[11];
  float* out = (float*)d_out;

  const int* srcp = ei;
  const int* dstp = ei + NE;

  float* ws = (float*)d_ws;
  float* h_buf = ws;                          // NN*NF f32 (gemm1 out, then gemm2 out)
  float* asb   = h_buf + (size_t)NN * NF;     // NN*NH
  float* adb   = asb + NN * NH;               // NN*NH
  unsigned short* xs_hi = (unsigned short*)(adb + NN * NH);  // NN*128
  unsigned short* xs_lo = xs_hi + (size_t)NN * 128;
  unsigned short* wt1h  = xs_lo + (size_t)NN * 128;          // 512*128
  unsigned short* wt1l  = wt1h + 512 * 128;
  unsigned short* wt2h  = wt1l + 512 * 128;                  // 512*512
  unsigned short* wt2l  = wt2h + 512 * 512;
  unsigned short* y1h   = wt2l + 512 * 512;                  // NN*NF (agg1 out)
  unsigned short* y1l   = y1h + (size_t)NN * NF;
  int* counts  = (int*)(y1l + (size_t)NN * NF);  // NN
  int* cursor  = counts + NN;                    // NN (adjacent: single memset)
  int* row_ptr = cursor + NN;                    // NN+1
  int* csr_src = row_ptr + NN + 1;               // NE

  // CSR build
  hipMemsetAsync(counts, 0, 2 * NN * sizeof(int), stream);  // counts + cursor
  hist_kernel<<<(NE + 255) / 256, 256, 0, stream>>>(dstp, counts);
  scan_fast<<<1, 1024, 0, stream>>>(counts, row_ptr);
  scatter_src<<<(NE + 255) / 256, 256, 0, stream>>>(srcp, dstp, row_ptr, cursor, csr_src);

  // pre-splits
  split_kernel<<<(NN * 128 / 4 + 255) / 256, 256, 0, stream>>>(x, xs_hi, xs_lo, NN * 128 / 4);
  tsplit_kernel<<<dim3(512 / 32, 128 / 32), 256, 0, stream>>>(W1, wt1h, wt1l, 128, 512);
  tsplit_kernel<<<dim3(512 / 32, 512 / 32), 256, 0, stream>>>(W2, wt2h, wt2l, 512, 512);

  dim3 ggrid(NF / GBN, (NN + GBM - 1) / GBM);

  // ---- layer 1 ----
  gemm_bf16<<<ggrid, 256, 0, stream>>>(xs_hi, xs_lo, wt1h, wt1l, h_buf, NN, 128, NF);
  att_logits_v<<<NN / 4, 256, 0, stream>>>(h_buf, at_s1, at_d1, asb, adb);
  agg64<1><<<NN / 4, 256, 0, stream>>>(h_buf, t1, csr_src, row_ptr, asb, adb, b1,
                                       nullptr, y1h, y1l);

  // ---- layer 2 ----
  gemm_bf16<<<ggrid, 256, 0, stream>>>(y1h, y1l, wt2h, wt2l, h_buf, NN, NF, NF);
  att_logits_v<<<NN / 4, 256, 0, stream>>>(h_buf, at_s2, at_d2, asb, adb);
  agg64<0><<<NN / 4, 256, 0, stream>>>(h_buf, t2, csr_src, row_ptr, asb, adb, b2,
                                       out, nullptr, nullptr);
}

// Round 13
// 277.942 us; speedup vs baseline: 1.0422x; 1.0422x over previous
//
#include <hip/hip_runtime.h>
#include <hip/hip_bf16.h>

#define NN 10000
#define NE 160000
#define NH 8
#define NC 64
#define NF 512   // NH*NC
#define NEG_SLOPE 0.2f
#define SEPS 1e-16f
#define L2E 1.44269504f

typedef __attribute__((ext_vector_type(8))) short s8v;   // 8 bf16 (4 VGPRs)
typedef __attribute__((ext_vector_type(4))) float f4v;   // MFMA accumulator
typedef __attribute__((ext_vector_type(2))) float f2v;   // packed f32 pair (v_pk_*)

__device__ __forceinline__ float lrelu(float x) { return x > 0.f ? x : NEG_SLOPE * x; }

__device__ __forceinline__ unsigned short bf16_rn(float f) {
  unsigned int u = __float_as_uint(f);
  return (unsigned short)((u + 0x7FFFu + ((u >> 16) & 1u)) >> 16);
}
__device__ __forceinline__ float bf16_to_f32(unsigned short h) {
  return __uint_as_float(((unsigned int)h) << 16);
}

// ------------------------- CSR build -------------------------
__global__ void hist_kernel(const int* __restrict__ dst, int* __restrict__ counts) {
  int e = blockIdx.x * blockDim.x + threadIdx.x;
  if (e < NE) atomicAdd(&counts[dst[e]], 1);
}

__global__ __launch_bounds__(1024) void scan_fast(const int* __restrict__ counts,
                                                  int* __restrict__ row_ptr) {
  __shared__ int part[1024];
  const int tid = threadIdx.x;
  const int base = tid * 16;
  int loc[16];
  int s = 0;
#pragma unroll
  for (int i = 0; i < 16; ++i) {
    int idx = base + i;
    int v = (idx < NN) ? counts[idx] : 0;
    loc[i] = s;
    s += v;
  }
  part[tid] = s;
  __syncthreads();
  for (int off = 1; off < 1024; off <<= 1) {
    int t = (tid >= off) ? part[tid - off] : 0;
    __syncthreads();
    part[tid] += t;
    __syncthreads();
  }
  int pre = (tid > 0) ? part[tid - 1] : 0;
#pragma unroll
  for (int i = 0; i < 16; ++i) {
    int idx = base + i;
    if (idx < NN) row_ptr[idx] = pre + loc[i];
  }
  if (tid == 1023) row_ptr[NN] = part[1023];
}

// store src VALUES sorted by dst (removes a gather level in agg)
__global__ void scatter_src(const int* __restrict__ src, const int* __restrict__ dst,
                            const int* __restrict__ row_ptr, int* __restrict__ cursor,
                            int* __restrict__ csr_src) {
  int e = blockIdx.x * blockDim.x + threadIdx.x;
  if (e < NE) {
    int d = dst[e];
    int r = atomicAdd(&cursor[d], 1);
    csr_src[row_ptr[d] + r] = src[e];
  }
}

// ---------------- f32 -> bf16 hi/lo split (elementwise) ----------------------
__global__ void split_kernel(const float* __restrict__ in, unsigned short* __restrict__ hi,
                             unsigned short* __restrict__ lo, int n4) {
  int i = blockIdx.x * blockDim.x + threadIdx.x;
  if (i < n4) {
    float4 v = ((const float4*)in)[i];
    float a[4] = {v.x, v.y, v.z, v.w};
    ushort4 h, l;
    unsigned short* hp = (unsigned short*)&h;
    unsigned short* lp = (unsigned short*)&l;
#pragma unroll
    for (int q = 0; q < 4; ++q) {
      unsigned short hb = bf16_rn(a[q]);
      hp[q] = hb;
      lp[q] = bf16_rn(a[q] - bf16_to_f32(hb));
    }
    ((ushort4*)hi)[i] = h;
    ((ushort4*)lo)[i] = l;
  }
}

// ------------- W[K][N] -> WT_hi/lo[N][K] transpose + split -------------------
__global__ __launch_bounds__(256) void tsplit_kernel(const float* __restrict__ W,
                                                     unsigned short* __restrict__ th,
                                                     unsigned short* __restrict__ tl,
                                                     int K, int N) {
  __shared__ float t[32][33];
  const int bx = blockIdx.x * 32;  // N base
  const int by = blockIdx.y * 32;  // K base
  const int lx = threadIdx.x & 31, ly = threadIdx.x >> 5;
#pragma unroll
  for (int r = 0; r < 32; r += 8)
    t[ly + r][lx] = W[(size_t)(by + ly + r) * N + bx + lx];
  __syncthreads();
#pragma unroll
  for (int r = 0; r < 32; r += 8) {
    float v = t[lx][ly + r];
    unsigned short hb = bf16_rn(v);
    size_t o = (size_t)(bx + ly + r) * K + by + lx;
    th[o] = hb;
    tl[o] = bf16_rn(v - bf16_to_f32(hb));
  }
}

// ---------------- MFMA GEMM with pre-split bf16 inputs (LDS-staged) ----------
// C[M][N] = A[M][K] @ B[K][N], B given transposed+split: BT[N][K].
// Tile 128x64, BK=32, 4 waves (2M x 2N). hi/lo 3-product MFMA.
// LDS fragment-major, slot unit 16B. [round-4 verified: absmax 3.05e-5]
#define GBM 128
#define GBN 64
#define GBK 32

__global__ __launch_bounds__(256) void gemm_bf16(const unsigned short* __restrict__ Ahi,
                                                 const unsigned short* __restrict__ Alo,
                                                 const unsigned short* __restrict__ BThi,
                                                 const unsigned short* __restrict__ BTlo,
                                                 float* __restrict__ C,
                                                 int M, int K, int N) {
  __shared__ s8v smem[1536];  // AH[512] AL[512] BH[256] BL[256]
  const int tid = threadIdx.x;
  const int m0 = blockIdx.y * GBM, n0 = blockIdx.x * GBN;
  const int wid = tid >> 6, lane = tid & 63;
  const int wm = wid >> 1, wn = wid & 1;
  const int lr = lane & 15, lb = lane >> 4;

  f4v acc[4][2];
  const f4v fzero = {0.f, 0.f, 0.f, 0.f};
#pragma unroll
  for (int m = 0; m < 4; ++m)
#pragma unroll
    for (int n = 0; n < 2; ++n) acc[m][n] = fzero;

  const int arow = tid >> 1, akh = tid & 1;
  const bool avalid = (m0 + arow) < M;
  const int aslot = ((arow >> 4) * 4 + akh * 2) * 16 + (arow & 15);
  const int bcol = tid >> 2, bkq = tid & 3;
  const int bslot = ((bcol >> 4) * 4 + bkq) * 16 + (bcol & 15);
  const s8v zv = {0, 0, 0, 0, 0, 0, 0, 0};

  for (int k0 = 0; k0 < K; k0 += GBK) {
    s8v a_h0 = zv, a_h1 = zv, a_l0 = zv, a_l1 = zv, b_h, b_l;
    if (avalid) {
      const unsigned short* ap = &Ahi[(size_t)(m0 + arow) * K + k0 + akh * 16];
      const unsigned short* alp = &Alo[(size_t)(m0 + arow) * K + k0 + akh * 16];
      a_h0 = *(const s8v*)ap;
      a_h1 = *(const s8v*)(ap + 8);
      a_l0 = *(const s8v*)alp;
      a_l1 = *(const s8v*)(alp + 8);
    }
    {
      const unsigned short* bp = &BThi[(size_t)(n0 + bcol) * K + k0 + bkq * 8];
      const unsigned short* blp = &BTlo[(size_t)(n0 + bcol) * K + k0 + bkq * 8];
      b_h = *(const s8v*)bp;
      b_l = *(const s8v*)blp;
    }
    __syncthreads();
    smem[aslot] = a_h0;
    smem[aslot + 16] = a_h1;
    smem[512 + aslot] = a_l0;
    smem[512 + aslot + 16] = a_l1;
    smem[1024 + bslot] = b_h;
    smem[1280 + bslot] = b_l;
    __syncthreads();
    s8v ah[4], al[4], bh[2], bl[2];
#pragma unroll
    for (int m = 0; m < 4; ++m) {
      int slot = ((wm * 4 + m) * 4 + lb) * 16 + lr;
      ah[m] = smem[slot];
      al[m] = smem[512 + slot];
    }
#pragma unroll
    for (int n = 0; n < 2; ++n) {
      int slot = ((wn * 2 + n) * 4 + lb) * 16 + lr;
      bh[n] = smem[1024 + slot];
      bl[n] = smem[1280 + slot];
    }
#pragma unroll
    for (int m = 0; m < 4; ++m)
#pragma unroll
      for (int n = 0; n < 2; ++n) {
        acc[m][n] = __builtin_amdgcn_mfma_f32_16x16x32_bf16(ah[m], bh[n], acc[m][n], 0, 0, 0);
        acc[m][n] = __builtin_amdgcn_mfma_f32_16x16x32_bf16(ah[m], bl[n], acc[m][n], 0, 0, 0);
        acc[m][n] = __builtin_amdgcn_mfma_f32_16x16x32_bf16(al[m], bh[n], acc[m][n], 0, 0, 0);
      }
  }
#pragma unroll
  for (int m = 0; m < 4; ++m) {
    int row = m0 + wm * 64 + m * 16 + lb * 4;
#pragma unroll
    for (int n = 0; n < 2; ++n) {
      int col = n0 + wn * 32 + n * 16 + lr;
#pragma unroll
      for (int j = 0; j < 4; ++j) {
        if (row + j < M) C[(size_t)(row + j) * N + col] = acc[m][n][j];
      }
    }
  }
}

// ------------------- per-node attention logits (4 nodes/block) ---------------
__global__ __launch_bounds__(256) void att_logits_v(const float* __restrict__ h,
                                                    const float* __restrict__ att_src,
                                                    const float* __restrict__ att_dst,
                                                    float* __restrict__ as_,
                                                    float* __restrict__ ad_) {
  const int n = blockIdx.x * 4 + (threadIdx.x >> 6);
  const int lane = threadIdx.x & 63;
  const float4* hp = (const float4*)&h[(size_t)n * NF];
  float4 v0 = hp[lane * 2], v1 = hp[lane * 2 + 1];
  const int base = lane * 8;
  const float4* sp = (const float4*)&att_src[base];
  const float4* dp = (const float4*)&att_dst[base];
  float4 s0 = sp[0], s1 = sp[1], d0 = dp[0], d1 = dp[1];
  float s = v0.x * s0.x + v0.y * s0.y + v0.z * s0.z + v0.w * s0.w +
            v1.x * s1.x + v1.y * s1.y + v1.z * s1.z + v1.w * s1.w;
  float d = v0.x * d0.x + v0.y * d0.y + v0.z * d0.z + v0.w * d0.w +
            v1.x * d1.x + v1.y * d1.y + v1.z * d1.z + v1.w * d1.w;
#pragma unroll
  for (int off = 1; off <= 4; off <<= 1) {
    s += __shfl_xor(s, off);
    d += __shfl_xor(d, off);
  }
  if ((lane & 7) == 0) {
    int hd = lane >> 3;
    as_[n * NH + hd] = s;
    ad_[n * NH + hd] = d;
  }
}

// ---------------- fused edge-softmax + softmax-aggregation -------------------
// 4 dst nodes per 256-thread block, one 64-lane wave per node. Edge src values
// shfl-broadcast from registers; 8 channels/lane (32B coalesced h loads).
// Pass-2 is 4-edge software-batched: 4 shfls + 4 as_ loads + 8 h-loads are
// issued before any consume (round-11 was latency-serialized per edge).
// Channel math on f2v so the compiler emits packed v_pk_{mul,add,fma}_f32.
// Plain (non-shifted) softmax: logits O(1-10), f32 exp cannot overflow.
// NOTE: every __shfl must execute with a wave-uniform trip count (round-5 bug).
__device__ __forceinline__ void acc_edge(float4 ha, float4 hb, float al, float tl2,
                                         f2v S[4], f2v O[4]) {
  f2v m0 = f2v{ha.x, ha.y} * al;
  f2v m1 = f2v{ha.z, ha.w} * al;
  f2v m2 = f2v{hb.x, hb.y} * al;
  f2v m3 = f2v{hb.z, hb.w} * al;
  f2v e0 = {__builtin_exp2f(tl2 * m0[0]), __builtin_exp2f(tl2 * m0[1])};
  f2v e1 = {__builtin_exp2f(tl2 * m1[0]), __builtin_exp2f(tl2 * m1[1])};
  f2v e2 = {__builtin_exp2f(tl2 * m2[0]), __builtin_exp2f(tl2 * m2[1])};
  f2v e3 = {__builtin_exp2f(tl2 * m3[0]), __builtin_exp2f(tl2 * m3[1])};
  S[0] += e0; O[0] += e0 * m0;
  S[1] += e1; O[1] += e1 * m1;
  S[2] += e2; O[2] += e2 * m2;
  S[3] += e3; O[3] += e3 * m3;
}

template <int SPLITOUT>
__global__ __launch_bounds__(256) void agg64(const float* __restrict__ h,
                                             const float* __restrict__ tptr,
                                             const int* __restrict__ csr_src,
                                             const int* __restrict__ row_ptr,
                                             const float* __restrict__ as_,
                                             const float* __restrict__ ad_,
                                             const float* __restrict__ bias,
                                             float* __restrict__ outf,
                                             unsigned short* __restrict__ outh,
                                             unsigned short* __restrict__ outl) {
  const int n = blockIdx.x * 4 + (threadIdx.x >> 6);
  const int lane = threadIdx.x & 63;
  const int start = row_ptr[n];
  const int deg = row_ptr[n + 1] - start;
  const int hd1 = lane & 7;   // pass-1 head
  const int jof = lane >> 3;  // pass-1 edge offset
  const int hd2 = lane >> 3;  // pass-2 head (channels c..c+7 all in this head)
  const int c = lane * 8;
  const float tl2 = tptr[0] * L2E;
  const float adv = ad_[n * NH + hd1];

  // ---- pass 1: per-head attention-softmax denominator ----
  // uniform trip count; shfl source clamped to an active lane; masked add
  float den = 0.f;
  for (int base = 0; base < deg; base += 64) {
    int cnt = min(deg - base, 64);
    int mysrc = csr_src[start + base + min(lane, cnt - 1)];
    int trips = (cnt + 7) >> 3;
    for (int i = 0; i < trips; ++i) {
      int j = jof + (i << 3);
      int sn = __shfl(mysrc, min(j, cnt - 1));
      float v = __builtin_exp2f(L2E * lrelu(as_[sn * NH + hd1] + adv));
      den += (j < cnt) ? v : 0.f;
    }
  }
  den += __shfl_xor(den, 8);
  den += __shfl_xor(den, 16);
  den += __shfl_xor(den, 32);
  float invd = 1.f / (den + SEPS);
  // lanes 0..7 hold heads 0..7; redistribute for pass-2 mapping
  float inv2 = __shfl(invd, hd2);
  float adv2 = __shfl(adv, hd2);

  // ---- pass 2: per-channel softmax-weighted aggregation (4-edge batched) ----
  f2v S[4], O[4];
#pragma unroll
  for (int p = 0; p < 4; ++p) { S[p] = f2v{0.f, 0.f}; O[p] = f2v{0.f, 0.f}; }
  for (int base = 0; base < deg; base += 64) {
    int cnt = min(deg - base, 64);
    int mysrc = csr_src[start + base + min(lane, cnt - 1)];
    int k = 0;
    for (; k + 4 <= cnt; k += 4) {  // wave-uniform condition: all lanes active
      int sn0 = __shfl(mysrc, k + 0);
      int sn1 = __shfl(mysrc, k + 1);
      int sn2 = __shfl(mysrc, k + 2);
      int sn3 = __shfl(mysrc, k + 3);
      float av0 = as_[sn0 * NH + hd2];
      float av1 = as_[sn1 * NH + hd2];
      float av2 = as_[sn2 * NH + hd2];
      float av3 = as_[sn3 * NH + hd2];
      const float* p0 = &h[(size_t)sn0 * NF + c];
      const float* p1 = &h[(size_t)sn1 * NF + c];
      const float* p2 = &h[(size_t)sn2 * NF + c];
      const float* p3 = &h[(size_t)sn3 * NF + c];
      float4 a0 = *(const float4*)p0, b0 = *(const float4*)(p0 + 4);
      float4 a1 = *(const float4*)p1, b1 = *(const float4*)(p1 + 4);
      float4 a2 = *(const float4*)p2, b2 = *(const float4*)(p2 + 4);
      float4 a3 = *(const float4*)p3, b3 = *(const float4*)(p3 + 4);
      float al0 = __builtin_exp2f(L2E * lrelu(av0 + adv2)) * inv2;
      float al1 = __builtin_exp2f(L2E * lrelu(av1 + adv2)) * inv2;
      float al2 = __builtin_exp2f(L2E * lrelu(av2 + adv2)) * inv2;
      float al3 = __builtin_exp2f(L2E * lrelu(av3 + adv2)) * inv2;
      acc_edge(a0, b0, al0, tl2, S, O);
      acc_edge(a1, b1, al1, tl2, S, O);
      acc_edge(a2, b2, al2, tl2, S, O);
      acc_edge(a3, b3, al3, tl2, S, O);
    }
    for (; k < cnt; ++k) {  // remainder, wave-uniform
      int sn = __shfl(mysrc, k);
      float av = as_[sn * NH + hd2];
      float alv = __builtin_exp2f(L2E * lrelu(av + adv2)) * inv2;
      const float* hp = &h[(size_t)sn * NF + c];
      float4 ha = *(const float4*)hp;
      float4 hb = *(const float4*)(hp + 4);
      acc_edge(ha, hb, alv, tl2, S, O);
    }
  }
  float r[8];
#pragma unroll
  for (int p = 0; p < 4; ++p) {
    r[2 * p]     = fmaxf(O[p][0] / (S[p][0] + SEPS) + bias[c + 2 * p], 0.f);
    r[2 * p + 1] = fmaxf(O[p][1] / (S[p][1] + SEPS) + bias[c + 2 * p + 1], 0.f);
  }

  if (SPLITOUT) {
    short hh[8], ll[8];
#pragma unroll
    for (int q = 0; q < 8; ++q) {
      unsigned short hb = bf16_rn(r[q]);
      hh[q] = (short)hb;
      ll[q] = (short)bf16_rn(r[q] - bf16_to_f32(hb));
    }
    *(s8v*)(outh + (size_t)n * NF + c) = s8v{hh[0], hh[1], hh[2], hh[3], hh[4], hh[5], hh[6], hh[7]};
    *(s8v*)(outl + (size_t)n * NF + c) = s8v{ll[0], ll[1], ll[2], ll[3], ll[4], ll[5], ll[6], ll[7]};
  } else {
    float* op = &outf[(size_t)n * NF + c];
    *(float4*)op = make_float4(r[0], r[1], r[2], r[3]);
    *(float4*)(op + 4) = make_float4(r[4], r[5], r[6], r[7]);
  }
}

// ------------------------- launch -------------------------
extern "C" void kernel_launch(void* const* d_in, const int* in_sizes, int n_in,
                              void* d_out, int out_size, void* d_ws, size_t ws_size,
                              hipStream_t stream) {
  const float* x     = (const float*)d_in[0];
  const int*   ei    = (const int*)d_in[1];
  const float* W1    = (const float*)d_in[2];
  const float* at_s1 = (const float*)d_in[3];
  const float* at_d1 = (const float*)d_in[4];
  const float* b1    = (const float*)d_in[5];
  const float* t1    = (const float*)d_in[6];
  const float* W2    = (const float*)d_in[7];
  const float* at_s2 = (const float*)d_in[8];
  const float* at_d2 = (const float*)d_in[9];
  const float* b2    = (const float*)d_in[10];
  const float* t2    = (const float*)d_in[11];
  float* out = (float*)d_out;

  const int* srcp = ei;
  const int* dstp = ei + NE;

  float* ws = (float*)d_ws;
  float* h_buf = ws;                          // NN*NF f32 (gemm1 out, then gemm2 out)
  float* asb   = h_buf + (size_t)NN * NF;     // NN*NH
  float* adb   = asb + NN * NH;               // NN*NH
  unsigned short* xs_hi = (unsigned short*)(adb + NN * NH);  // NN*128
  unsigned short* xs_lo = xs_hi + (size_t)NN * 128;
  unsigned short* wt1h  = xs_lo + (size_t)NN * 128;          // 512*128
  unsigned short* wt1l  = wt1h + 512 * 128;
  unsigned short* wt2h  = wt1l + 512 * 128;                  // 512*512
  unsigned short* wt2l  = wt2h + 512 * 512;
  unsigned short* y1h   = wt2l + 512 * 512;                  // NN*NF (agg1 out)
  unsigned short* y1l   = y1h + (size_t)NN * NF;
  int* counts  = (int*)(y1l + (size_t)NN * NF);  // NN
  int* cursor  = counts + NN;                    // NN (adjacent: single memset)
  int* row_ptr = cursor + NN;                    // NN+1
  int* csr_src = row_ptr + NN + 1;               // NE

  // CSR build
  hipMemsetAsync(counts, 0, 2 * NN * sizeof(int), stream);  // counts + cursor
  hist_kernel<<<(NE + 255) / 256, 256, 0, stream>>>(dstp, counts);
  scan_fast<<<1, 1024, 0, stream>>>(counts, row_ptr);
  scatter_src<<<(NE + 255) / 256, 256, 0, stream>>>(srcp, dstp, row_ptr, cursor, csr_src);

  // pre-splits
  split_kernel<<<(NN * 128 / 4 + 255) / 256, 256, 0, stream>>>(x, xs_hi, xs_lo, NN * 128 / 4);
  tsplit_kernel<<<dim3(512 / 32, 128 / 32), 256, 0, stream>>>(W1, wt1h, wt1l, 128, 512);
  tsplit_kernel<<<dim3(512 / 32, 512 / 32), 256, 0, stream>>>(W2, wt2h, wt2l, 512, 512);

  dim3 ggrid(NF / GBN, (NN + GBM - 1) / GBM);

  // ---- layer 1 ----
  gemm_bf16<<<ggrid, 256, 0, stream>>>(xs_hi, xs_lo, wt1h, wt1l, h_buf, NN, 128, NF);
  att_logits_v<<<NN / 4, 256, 0, stream>>>(h_buf, at_s1, at_d1, asb, adb);
  agg64<1><<<NN / 4, 256, 0, stream>>>(h_buf, t1, csr_src, row_ptr, asb, adb, b1,
                                       nullptr, y1h, y1l);

  // ---- layer 2 ----
  gemm_bf16<<<ggrid, 256, 0, stream>>>(y1h, y1l, wt2h, wt2l, h_buf, NN, NF, NF);
  att_logits_v<<<NN / 4, 256, 0, stream>>>(h_buf, at_s2, at_d2, asb, adb);
  agg64<0><<<NN / 4, 256, 0, stream>>>(h_buf, t2, csr_src, row_ptr, asb, adb, b2,
                                       out, nullptr, nullptr);
}